// Round 2
// baseline (1015.576 us; speedup 1.0000x reference)
//
#include <hip/hip_runtime.h>
#include <hip/hip_bf16.h>
#include <math.h>

#define NB 4096
#define NN 64
#define NM 4
#define NF 128
#define NOBS 64
#define ND 64
#define NH 4
#define NLAYER 2
#define NFF 128
#define NHID 64
#define NOUT 8
#define EPSC 1e-6f

typedef __attribute__((ext_vector_type(8))) short short8;
typedef __attribute__((ext_vector_type(4))) float floatx4;

struct GParams {
    const float* x_anc; const float* g_anc; const float* x_nei; const float* ew_anc;
    const float* W_anc; const float* b_anc;
    const float* Wv_emb; const float* bv_emb; const float* Wv_val; const float* bv_val;
    const float* r_Win; const float* r_bin; const float* r_lng; const float* r_lnb;
    const float* r_W1; const float* r_b1; const float* r_W2; const float* r_b2;
    const float* r_Wview; const float* r_bview; const float* r_Wmode; const float* r_bmode;
    const float* log_tau;
    const float* L_Wq; const float* L_Wk; const float* L_Wv; const float* L_Wo;
    const float* L_ln1g; const float* L_ln1b; const float* L_ln2g; const float* L_ln2b;
    const float* L_Wf1; const float* L_bf1; const float* L_Wf2; const float* L_bf2;
    const float* p_lng; const float* p_lnb; const float* p_W1; const float* p_b1;
    const float* p_W2; const float* p_b2;
    float* out;
};

__device__ __forceinline__ float gelu_f(float x) {
    return 0.5f * x * (1.0f + erff(x * 0.7071067811865476f));
}
__device__ __forceinline__ float wsum64(float v) {
#pragma unroll
    for (int off = 32; off > 0; off >>= 1) v += __shfl_xor(v, off, 64);
    return v;
}
__device__ __forceinline__ float wmax64(float v) {
#pragma unroll
    for (int off = 32; off > 0; off >>= 1) v = fmaxf(v, __shfl_xor(v, off, 64));
    return v;
}
// bf16 round-nearest-even, bit-level (finite inputs only)
__device__ __forceinline__ unsigned short f2bf(float f) {
    unsigned int u = __float_as_uint(f);
    unsigned int r = (u + 0x7fffu + ((u >> 16) & 1u)) >> 16;
    return (unsigned short)r;
}
__device__ __forceinline__ float bf2f(unsigned short s) {
    return __uint_as_float(((unsigned int)s) << 16);
}

__global__ __launch_bounds__(256, 4)
void gora_fused(GParams P)
{
    const int b = blockIdx.x;
    const int t = threadIdx.x;
    const int lane = t & 63;
    const int wave = t >> 6;
    const int l16 = lane & 15;   // col / m within 16x16 tile
    const int q4  = lane >> 4;   // quad

    // ---- LDS: region1 (x_nei staging) aliased with K/V buffers ----
    __shared__ __align__(16) union Reg1 {
        unsigned short xsf[NN * 136];                       // 17408 B (pad 136 breaks MFMA-A conflicts)
        struct { unsigned short kb[NN * 66]; unsigned short vb[NN * 66]; } kv; // 16896 B
    } R1;
    __shared__ __align__(16) unsigned short hb[NN * 72];    // h_nei_shared bf16, padded rows
    __shared__ float ew_s[NN * NM];
    __shared__ float winv[NM], wssum[NM];
    __shared__ float xw[NM][NF];
    __shared__ float hv[NM][ND];
    __shared__ float pvc[NM][ND];
    __shared__ float part[4][NF];                           // cross-wave partials
    __shared__ float hfin[NHID];
    __shared__ float pi_raw[16];
    __shared__ float pi_s[16];
    __shared__ float beta_s[NH];
    __shared__ float gate_s[NH * NN];
    __shared__ float xcur[ND];
    __shared__ float qv[ND];
    __shared__ float attn_s[NH * NN];
    __shared__ float ctx_s[ND];
    __shared__ float ffs[NFF];
    __shared__ float sA[ND];
    __shared__ float sB[ND];

    // ================= E0: loads =================
    {
        float e = P.ew_anc[(size_t)b * 256 + t];
        ew_s[t] = (e > 0.0f) ? e : 0.0f;
    }
    {
        const float4* xn4 = (const float4*)(P.x_nei + (size_t)b * NN * NF);
#pragma unroll
        for (int i = 0; i < 4; i++) {
            int p = t + i * 256;                 // float8 index, 1024 total
            float4 a0 = xn4[2 * p];
            float4 a1 = xn4[2 * p + 1];
            int e8 = p * 8, n = e8 >> 7, f = e8 & 127;
            short8 s;
            s[0] = (short)f2bf(a0.x); s[1] = (short)f2bf(a0.y);
            s[2] = (short)f2bf(a0.z); s[3] = (short)f2bf(a0.w);
            s[4] = (short)f2bf(a1.x); s[5] = (short)f2bf(a1.y);
            s[6] = (short)f2bf(a1.z); s[7] = (short)f2bf(a1.w);
            *(short8*)&R1.xsf[n * 136 + f] = s;
        }
    }
    __syncthreads();

    // ======== E1: view-weight norms + h_anc partials (4-way split) ========
    if (t < NM) {
        float ssum = 0.0f;
        for (int n = 0; n < NN; n++) ssum += ew_s[n * 4 + t];
        float c = fmaxf(ssum, EPSC);
        winv[t] = 1.0f / c;
        wssum[t] = ssum / c;
    }
    {
        const float* xa = P.x_anc + (size_t)b * NF;
        float acc = 0.0f;
        for (int f = wave * 32; f < wave * 32 + 32; f++)
            acc += xa[f] * P.W_anc[f * ND + lane];
        part[wave][lane] = acc;
    }
    __syncthreads();

    // ======== E2: xcur = h_anc (merge) ; xw[m][f] ========
    if (t < ND)
        xcur[t] = P.b_anc[t] + part[0][t] + part[1][t] + part[2][t] + part[3][t];
    {
        int f = t & 127, m0 = t >> 7;
        float a0 = 0.f, a1 = 0.f;
        for (int n = 0; n < NN; n++) {
            float xv = bf2f(R1.xsf[n * 136 + f]);
            a0 += ew_s[n * 4 + m0] * xv;
            a1 += ew_s[n * 4 + m0 + 2] * xv;
        }
        xw[m0][f]     = a0 * winv[m0];
        xw[m0 + 2][f] = a1 * winv[m0 + 2];
    }
    __syncthreads();

    // ======== E3: h_nei_shared via MFMA (4 waves x 16-row strips) + hv ========
    {
        const int m0 = wave * 16;
        floatx4 acc[4];
#pragma unroll
        for (int nt = 0; nt < 4; nt++) acc[nt] = (floatx4){0.f, 0.f, 0.f, 0.f};
        const float* W0 = P.Wv_emb;  // view m=0 block, [f][d] row-major
#pragma unroll
        for (int k0 = 0; k0 < NF; k0 += 32) {
            short8 a = *(const short8*)&R1.xsf[(m0 + l16) * 136 + k0 + q4 * 8];
#pragma unroll
            for (int nt = 0; nt < 4; nt++) {
                short8 bfr;
#pragma unroll
                for (int j = 0; j < 8; j++)
                    bfr[j] = (short)f2bf(W0[(k0 + q4 * 8 + j) * ND + nt * 16 + l16]);
                acc[nt] = __builtin_amdgcn_mfma_f32_16x16x32_bf16(a, bfr, acc[nt], 0, 0, 0);
            }
        }
#pragma unroll
        for (int nt = 0; nt < 4; nt++) {
            float bias = P.bv_emb[nt * 16 + l16];
#pragma unroll
            for (int r = 0; r < 4; r++) {
                int row = m0 + q4 * 4 + r;
                hb[row * 72 + nt * 16 + l16] = f2bf(acc[nt][r] + bias);
            }
        }
    }
    {   // hv[m=wave][d=lane] = xw[m] @ Wv_emb[m] + s*bias
        int m = wave, d = lane;
        float acc = wssum[m] * P.bv_emb[m * ND + d];
        const float* We = P.Wv_emb + (size_t)m * NF * ND;
        for (int f = 0; f < NF; f++) acc += xw[m][f] * We[f * ND + d];
        hv[m][d] = acc;
    }
    __syncthreads();

    // ======== E4: pvc[m] = hv[m] @ Wv_val[m] + s*bias ========
    {
        int m = wave, d = lane;
        float acc = wssum[m] * P.bv_val[m * ND + d];
        const float* Wv = P.Wv_val + (size_t)m * ND * ND;
        for (int k = 0; k < ND; k++) acc += hv[m][k] * Wv[k * ND + d];
        pvc[m][d] = acc;
    }
    __syncthreads();

    // ======== E5: r_in partials over concat(g, ctx_vec) ========
    {
        int d = lane, w = wave;
        float acc = 0.0f;
        if (w < 2) {
            const float* ga = P.g_anc + (size_t)b * NOBS;
            for (int f = w * 32; f < w * 32 + 32; f++)
                acc += ga[f] * P.r_Win[f * NHID + d];
        } else {
            for (int f = (w - 2) * 32; f < (w - 2) * 32 + 32; f++) {
                float cv = 0.25f * (pvc[0][f] + pvc[1][f] + pvc[2][f] + pvc[3][f]);
                acc += cv * P.r_Win[(NOBS + f) * NHID + d];
            }
        }
        part[w][d] = acc;
    }
    __syncthreads();

    // ======== E6: LN + gelu -> sB ========
    if (t < ND) {
        float acc = P.r_bin[t] + part[0][t] + part[1][t] + part[2][t] + part[3][t];
        float mean = wsum64(acc) * (1.0f / 64.0f);
        float dv = acc - mean;
        float var = wsum64(dv * dv) * (1.0f / 64.0f);
        sB[t] = gelu_f(dv * rsqrtf(var + 1e-5f) * P.r_lng[t] + P.r_lnb[t]);
    }
    __syncthreads();

    // ======== E7/E8: r_W1 ========
    {
        int d = lane, w = wave;
        float acc = 0.0f;
        for (int k = w * 16; k < w * 16 + 16; k++) acc += sB[k] * P.r_W1[k * NHID + d];
        part[w][d] = acc;
    }
    __syncthreads();
    if (t < ND) sA[t] = gelu_f(P.r_b1[t] + part[0][t] + part[1][t] + part[2][t] + part[3][t]);
    __syncthreads();

    // ======== E9/E10: r_W2 ========
    {
        int d = lane, w = wave;
        float acc = 0.0f;
        for (int k = w * 16; k < w * 16 + 16; k++) acc += sA[k] * P.r_W2[k * NHID + d];
        part[w][d] = acc;
    }
    __syncthreads();
    if (t < ND) hfin[t] = gelu_f(P.r_b2[t] + part[0][t] + part[1][t] + part[2][t] + part[3][t]);
    __syncthreads();

    // ======== E11: pi_raw + beta ========
    if (t < 16) {
        int h = t >> 2, mm = t & 3;
        float acc = P.r_bview[t];
        for (int k = 0; k < NHID; k++) acc += hfin[k] * P.r_Wview[(h * NHID + k) * 4 + mm];
        pi_raw[t] = acc;
    } else if (t >= 64 && t < 64 + NH) {
        int h = t - 64;
        float acc = P.r_bmode[h];
        for (int k = 0; k < NHID; k++) acc += hfin[k] * P.r_Wmode[h * NHID + k];
        beta_s[h] = 1.0f / (1.0f + expf(-acc));
    }
    __syncthreads();

    // ======== E12: per-wave softmax(pi) + gate ========
    {
        int h = wave;
        float p0 = pi_raw[h * 4 + 0], p1 = pi_raw[h * 4 + 1];
        float p2 = pi_raw[h * 4 + 2], p3 = pi_raw[h * 4 + 3];
        float mx = fmaxf(fmaxf(p0, p1), fmaxf(p2, p3));
        float e0 = expf(p0 - mx), e1 = expf(p1 - mx), e2 = expf(p2 - mx), e3 = expf(p3 - mx);
        float inv = 1.0f / (e0 + e1 + e2 + e3);
        e0 *= inv; e1 *= inv; e2 *= inv; e3 *= inv;
        if (lane == 0) {
            pi_s[h * 4 + 0] = e0; pi_s[h * 4 + 1] = e1;
            pi_s[h * 4 + 2] = e2; pi_s[h * 4 + 3] = e3;
        }
        int n = lane;
        float wv = e0 * ew_s[n * 4 + 0] + e1 * ew_s[n * 4 + 1]
                 + e2 * ew_s[n * 4 + 2] + e3 * ew_s[n * 4 + 3];
        gate_s[h * 64 + n] = logf(wv + EPSC);
    }
    __syncthreads();

    // ======== attention + FF layers ========
    const float inv_tau = 0.25f * expf(-P.log_tau[wave]);   // scale=1/sqrt(16), /tau
    for (int l = 0; l < NLAYER; l++) {
        const float* Wq  = P.L_Wq  + l * ND * ND;
        const float* Wk  = P.L_Wk  + l * ND * ND;
        const float* Wvv = P.L_Wv  + l * ND * ND;
        const float* Wo  = P.L_Wo  + l * ND * ND;
        const float* ln1g = P.L_ln1g + l * ND;
        const float* ln1b = P.L_ln1b + l * ND;
        const float* ln2g = P.L_ln2g + l * ND;
        const float* ln2b = P.L_ln2b + l * ND;
        const float* Wf1 = P.L_Wf1 + l * ND * NFF;
        const float* bf1 = P.L_bf1 + l * NFF;
        const float* Wf2 = P.L_Wf2 + l * NFF * ND;
        const float* bf2 = P.L_bf2 + l * ND;

        // --- L-E1: K/V via MFMA (all waves) + Q (t<64, after) ---
        {
            const int m0 = wave * 16;
            floatx4 aK[4], aV[4];
#pragma unroll
            for (int nt = 0; nt < 4; nt++) {
                aK[nt] = (floatx4){0.f, 0.f, 0.f, 0.f};
                aV[nt] = (floatx4){0.f, 0.f, 0.f, 0.f};
            }
#pragma unroll
            for (int k0 = 0; k0 < ND; k0 += 32) {
                short8 a = *(const short8*)&hb[(m0 + l16) * 72 + k0 + q4 * 8];
#pragma unroll
                for (int nt = 0; nt < 4; nt++) {
                    short8 bk, bv;
#pragma unroll
                    for (int j = 0; j < 8; j++) {
                        int kk = k0 + q4 * 8 + j;
                        bk[j] = (short)f2bf(Wk[kk * ND + nt * 16 + l16]);
                        bv[j] = (short)f2bf(Wvv[kk * ND + nt * 16 + l16]);
                    }
                    aK[nt] = __builtin_amdgcn_mfma_f32_16x16x32_bf16(a, bk, aK[nt], 0, 0, 0);
                    aV[nt] = __builtin_amdgcn_mfma_f32_16x16x32_bf16(a, bv, aV[nt], 0, 0, 0);
                }
            }
#pragma unroll
            for (int nt = 0; nt < 4; nt++)
#pragma unroll
                for (int r = 0; r < 4; r++) {
                    int row = m0 + q4 * 4 + r;
                    R1.kv.kb[row * 66 + nt * 16 + l16] = f2bf(aK[nt][r]);
                    R1.kv.vb[row * 66 + nt * 16 + l16] = f2bf(aV[nt][r]);
                }
        }
        if (t < ND) {
            float acc = 0.0f;
            for (int k = 0; k < ND; k++) acc += xcur[k] * Wq[k * ND + t];
            qv[t] = acc;
        }
        __syncthreads();

        // --- L-E2: scores + softmax (wave = head) ---
        {
            int h = wave, n = lane;
            float s = 0.0f;
#pragma unroll
            for (int j = 0; j < 16; j++)
                s += qv[h * 16 + j] * bf2f(R1.kv.kb[n * 66 + h * 16 + j]);
            s = s * inv_tau + gate_s[h * 64 + n];
            float mx = wmax64(s);
            float e = expf(s - mx);
            float se = wsum64(e);
            attn_s[h * 64 + n] = e / se;
        }
        __syncthreads();

        // --- L-E3: ctx ---
        if (t < ND) {
            int h = t >> 4;
            float acc = 0.0f;
            for (int n = 0; n < NN; n++)
                acc += attn_s[h * 64 + n] * bf2f(R1.kv.vb[n * 66 + t]);
            ctx_s[t] = acc;
        }
        __syncthreads();

        // --- L-E4: Wo partials ---
        {
            int d = lane, w = wave;
            float acc = 0.0f;
            for (int c = w * 16; c < w * 16 + 16; c++) acc += ctx_s[c] * Wo[c * ND + d];
            part[w][d] = acc;
        }
        __syncthreads();

        // --- L-E5: residual + LN1 ---
        if (t < ND) {
            float xv = xcur[t] + part[0][t] + part[1][t] + part[2][t] + part[3][t];
            float mean = wsum64(xv) * (1.0f / 64.0f);
            float dv = xv - mean;
            float var = wsum64(dv * dv) * (1.0f / 64.0f);
            xcur[t] = dv * rsqrtf(var + 1e-5f) * ln1g[t] + ln1b[t];
        }
        __syncthreads();

        // --- L-E6: FF1 partials (256 threads: 128 outs x 2-way k-split) ---
        {
            int j = t & 127, w2 = t >> 7;
            float acc = 0.0f;
            for (int k = w2 * 32; k < w2 * 32 + 32; k++) acc += xcur[k] * Wf1[k * NFF + j];
            part[w2][j] = acc;
        }
        __syncthreads();

        // --- L-E7: gelu -> ffs ---
        if (t < NFF) ffs[t] = gelu_f(bf1[t] + part[0][t] + part[1][t]);
        __syncthreads();

        // --- L-E8: FF2 partials (4-way k-split) ---
        {
            int d = lane, w = wave;
            float acc = 0.0f;
            for (int k = w * 32; k < w * 32 + 32; k++) acc += ffs[k] * Wf2[k * ND + d];
            part[w][d] = acc;
        }
        __syncthreads();

        // --- L-E9: residual + LN2 ---
        if (t < ND) {
            float xv = xcur[t] + bf2[t] + part[0][t] + part[1][t] + part[2][t] + part[3][t];
            float mean = wsum64(xv) * (1.0f / 64.0f);
            float dv = xv - mean;
            float var = wsum64(dv * dv) * (1.0f / 64.0f);
            xcur[t] = dv * rsqrtf(var + 1e-5f) * ln2g[t] + ln2b[t];
        }
        __syncthreads();
    }

    // ======== blended + final head ========
    if (t < ND) {
        float acc = 0.0f;
#pragma unroll
        for (int h = 0; h < NH; h++) {
            float iso = pi_s[h * 4 + 0] * pvc[0][t] + pi_s[h * 4 + 1] * pvc[1][t]
                      + pi_s[h * 4 + 2] * pvc[2][t] + pi_s[h * 4 + 3] * pvc[3][t];
            acc += (1.0f - beta_s[h]) * iso + beta_s[h] * xcur[t];
        }
        float bl = acc * 0.25f;
        float mean = wsum64(bl) * (1.0f / 64.0f);
        float dv = bl - mean;
        float var = wsum64(dv * dv) * (1.0f / 64.0f);
        sA[t] = dv * rsqrtf(var + 1e-5f) * P.p_lng[t] + P.p_lnb[t];
    }
    __syncthreads();
    if (t < 32) {
        float acc = P.p_b1[t];
        for (int d = 0; d < ND; d++) acc += sA[d] * P.p_W1[d * 32 + t];
        sB[t] = gelu_f(acc);
    }
    __syncthreads();
    if (t < NOUT) {
        float acc = P.p_b2[t];
        for (int j = 0; j < 32; j++) acc += sB[j] * P.p_W2[j * NOUT + t];
        P.out[(size_t)b * NOUT + t] = acc;
    }
}

extern "C" void kernel_launch(void* const* d_in, const int* in_sizes, int n_in,
                              void* d_out, int out_size, void* d_ws, size_t ws_size,
                              hipStream_t stream)
{
    (void)in_sizes; (void)n_in; (void)d_ws; (void)ws_size; (void)out_size;
    GParams P;
    P.x_anc   = (const float*)d_in[0];
    P.g_anc   = (const float*)d_in[1];
    P.x_nei   = (const float*)d_in[2];
    P.ew_anc  = (const float*)d_in[3];
    P.W_anc   = (const float*)d_in[4];
    P.b_anc   = (const float*)d_in[5];
    P.Wv_emb  = (const float*)d_in[6];
    P.bv_emb  = (const float*)d_in[7];
    P.Wv_val  = (const float*)d_in[8];
    P.bv_val  = (const float*)d_in[9];
    P.r_Win   = (const float*)d_in[10];
    P.r_bin   = (const float*)d_in[11];
    P.r_lng   = (const float*)d_in[12];
    P.r_lnb   = (const float*)d_in[13];
    P.r_W1    = (const float*)d_in[14];
    P.r_b1    = (const float*)d_in[15];
    P.r_W2    = (const float*)d_in[16];
    P.r_b2    = (const float*)d_in[17];
    P.r_Wview = (const float*)d_in[18];
    P.r_bview = (const float*)d_in[19];
    P.r_Wmode = (const float*)d_in[20];
    P.r_bmode = (const float*)d_in[21];
    P.log_tau = (const float*)d_in[22];
    P.L_Wq    = (const float*)d_in[23];
    P.L_Wk    = (const float*)d_in[24];
    P.L_Wv    = (const float*)d_in[25];
    P.L_Wo    = (const float*)d_in[26];
    P.L_ln1g  = (const float*)d_in[27];
    P.L_ln1b  = (const float*)d_in[28];
    P.L_ln2g  = (const float*)d_in[29];
    P.L_ln2b  = (const float*)d_in[30];
    P.L_Wf1   = (const float*)d_in[31];
    P.L_bf1   = (const float*)d_in[32];
    P.L_Wf2   = (const float*)d_in[33];
    P.L_bf2   = (const float*)d_in[34];
    P.p_lng   = (const float*)d_in[35];
    P.p_lnb   = (const float*)d_in[36];
    P.p_W1    = (const float*)d_in[37];
    P.p_b1    = (const float*)d_in[38];
    P.p_W2    = (const float*)d_in[39];
    P.p_b2    = (const float*)d_in[40];
    P.out     = (float*)d_out;
    hipLaunchKernelGGL(gora_fused, dim3(NB), dim3(256), 0, stream, P);
}

// Round 4
// 779.173 us; speedup vs baseline: 1.3034x; 1.3034x over previous
//
#include <hip/hip_runtime.h>
#include <hip/hip_bf16.h>
#include <math.h>

#define NB 4096
#define NN 64
#define NM 4
#define NF 128
#define NOBS 64
#define ND 64
#define NH 4
#define NLAYER 2
#define NFF 128
#define NHID 64
#define NOUT 8
#define EPSC 1e-6f

// packed-weight layout in d_ws (unsigned short = bf16):
//   [0      , 8192 )  wE : Wv_emb view0, [col n=0..63][k=0..127]
//   [8192   , 16384)  wK : L_Wk, [l][col n][k]  (k=0..63)
//   [16384  , 24576)  wV : L_Wv, [l][col n][k]
#define WS_WE 0
#define WS_WK 8192
#define WS_WV 16384

typedef __attribute__((ext_vector_type(8))) short short8;
typedef __attribute__((ext_vector_type(4))) float floatx4;

struct GParams {
    const float* x_anc; const float* g_anc; const float* x_nei; const float* ew_anc;
    const float* W_anc; const float* b_anc;
    const float* Wv_emb; const float* bv_emb; const float* Wv_val; const float* bv_val;
    const float* r_Win; const float* r_bin; const float* r_lng; const float* r_lnb;
    const float* r_W1; const float* r_b1; const float* r_W2; const float* r_b2;
    const float* r_Wview; const float* r_bview; const float* r_Wmode; const float* r_bmode;
    const float* log_tau;
    const float* L_Wq; const float* L_Wk; const float* L_Wv; const float* L_Wo;
    const float* L_ln1g; const float* L_ln1b; const float* L_ln2g; const float* L_ln2b;
    const float* L_Wf1; const float* L_bf1; const float* L_Wf2; const float* L_bf2;
    const float* p_lng; const float* p_lnb; const float* p_W1; const float* p_b1;
    const float* p_W2; const float* p_b2;
    const unsigned short* wpack;
    float* out;
};

__device__ __forceinline__ float gelu_f(float x) {
    return 0.5f * x * (1.0f + erff(x * 0.7071067811865476f));
}
__device__ __forceinline__ float wsum64(float v) {
#pragma unroll
    for (int off = 32; off > 0; off >>= 1) v += __shfl_xor(v, off, 64);
    return v;
}
__device__ __forceinline__ float wmax64(float v) {
#pragma unroll
    for (int off = 32; off > 0; off >>= 1) v = fmaxf(v, __shfl_xor(v, off, 64));
    return v;
}
// bf16 round-nearest-even, bit-level (finite inputs only)
__device__ __forceinline__ unsigned short f2bf(float f) {
    unsigned int u = __float_as_uint(f);
    unsigned int r = (u + 0x7fffu + ((u >> 16) & 1u)) >> 16;
    return (unsigned short)r;
}
__device__ __forceinline__ float bf2f(unsigned short s) {
    return __uint_as_float(((unsigned int)s) << 16);
}
__device__ __forceinline__ unsigned int pack2(float lo, float hi) {
    return (unsigned int)f2bf(lo) | ((unsigned int)f2bf(hi) << 16);
}

// ---- prepack: fp32 weights -> bf16, B-fragment-friendly [col][k] layout ----
__global__ __launch_bounds__(256)
void prepack_w(const float* Wv_emb, const float* L_Wk, const float* L_Wv,
               unsigned short* ws)
{
    int i = blockIdx.x * 256 + threadIdx.x;          // 24576 total
    if (i < 8192) {
        int n = i >> 7, k = i & 127;                 // wE[n*128+k] = Wv_emb[0][k][n]
        ws[WS_WE + i] = f2bf(Wv_emb[k * ND + n]);
    } else if (i < 16384) {
        int j = i - 8192;
        int l = j >> 12, r = j & 4095, n = r >> 6, k = r & 63;
        ws[i] = f2bf(L_Wk[l * 4096 + k * ND + n]);
    } else if (i < 24576) {
        int j = i - 16384;
        int l = j >> 12, r = j & 4095, n = r >> 6, k = r & 63;
        ws[i] = f2bf(L_Wv[l * 4096 + k * ND + n]);
    }
}

__global__ __launch_bounds__(256, 4)
void gora_fused(GParams P)
{
    const int b = blockIdx.x;
    const int t = threadIdx.x;
    const int lane = t & 63;
    const int wave = t >> 6;
    const int l16 = lane & 15;   // col within 16x16 tile
    const int q4  = lane >> 4;   // quad

    // ---- LDS: region1 (x_nei staging) aliased with K/V buffers ----
    __shared__ __align__(16) union Reg1 {
        unsigned short xsf[NN * 136];                       // 17408 B
        struct { unsigned short kb[NN * 66]; unsigned short vb[NN * 66]; } kv;
    } R1;
    __shared__ __align__(16) unsigned short hb[NN * 72];    // h_nei_shared bf16
    __shared__ float ew_s[NN * NM];
    __shared__ float winv[NM], wssum[NM];
    __shared__ float xw[NM][NF];
    __shared__ float hv[NM][ND];
    __shared__ float pvc[NM][ND];
    __shared__ float part[4][NF];
    __shared__ float hfin[NHID];
    __shared__ float pi_raw[16];
    __shared__ float pi_s[16];
    __shared__ float beta_s[NH];
    __shared__ float gate_s[NH * NN];
    __shared__ float xcur[ND];
    __shared__ float qv[ND];
    __shared__ float attn_s[NH * NN];
    __shared__ float ctx_s[ND];
    __shared__ float ffs[NFF];
    __shared__ float sA[ND];
    __shared__ float sB[ND];

    // ================= E0: loads =================
    {
        float e = P.ew_anc[(size_t)b * 256 + t];
        ew_s[t] = (e > 0.0f) ? e : 0.0f;
    }
    {
        const float4* xn4 = (const float4*)(P.x_nei + (size_t)b * NN * NF);
#pragma unroll
        for (int i = 0; i < 4; i++) {
            int p = t + i * 256;                 // float8 index, 1024 total
            float4 a0 = xn4[2 * p];
            float4 a1 = xn4[2 * p + 1];
            int e8 = p * 8, n = e8 >> 7, f = e8 & 127;
            int4 pk;
            pk.x = (int)pack2(a0.x, a0.y);
            pk.y = (int)pack2(a0.z, a0.w);
            pk.z = (int)pack2(a1.x, a1.y);
            pk.w = (int)pack2(a1.z, a1.w);
            *(int4*)&R1.xsf[n * 136 + f] = pk;
        }
    }
    __syncthreads();

    // ======== E1: view-weight norms + h_anc partials ========
    if (t < NM) {
        float ssum = 0.0f;
        for (int n = 0; n < NN; n++) ssum += ew_s[n * 4 + t];
        float c = fmaxf(ssum, EPSC);
        winv[t] = 1.0f / c;
        wssum[t] = ssum / c;
    }
    {
        const float* xa = P.x_anc + (size_t)b * NF;
        float acc = 0.0f;
        for (int f = wave * 32; f < wave * 32 + 32; f++)
            acc += xa[f] * P.W_anc[f * ND + lane];
        part[wave][lane] = acc;
    }
    __syncthreads();

    // ======== E2: xcur = h_anc ; xw[m][f] ========
    if (t < ND)
        xcur[t] = P.b_anc[t] + part[0][t] + part[1][t] + part[2][t] + part[3][t];
    {
        int f = t & 127, m0 = t >> 7;
        float a0 = 0.f, a1 = 0.f;
        for (int n = 0; n < NN; n++) {
            float xv = bf2f(R1.xsf[n * 136 + f]);
            a0 += ew_s[n * 4 + m0] * xv;
            a1 += ew_s[n * 4 + m0 + 2] * xv;
        }
        xw[m0][f]     = a0 * winv[m0];
        xw[m0 + 2][f] = a1 * winv[m0 + 2];
    }
    __syncthreads();

    // ======== E3: h_nei_shared via MFMA (prepacked B) + hv ========
    {
        const int m0 = wave * 16;
        const unsigned short* wE = P.wpack + WS_WE;
#pragma unroll
        for (int nt = 0; nt < 4; nt++) {
            floatx4 c = (floatx4){0.f, 0.f, 0.f, 0.f};
#pragma unroll
            for (int k0 = 0; k0 < NF; k0 += 32) {
                short8 a  = *(const short8*)&R1.xsf[(m0 + l16) * 136 + k0 + q4 * 8];
                short8 bb = *(const short8*)&wE[(nt * 16 + l16) * 128 + k0 + q4 * 8];
                c = __builtin_amdgcn_mfma_f32_16x16x32_bf16(a, bb, c, 0, 0, 0);
            }
            float bias = P.bv_emb[nt * 16 + l16];
#pragma unroll
            for (int r = 0; r < 4; r++)
                hb[(m0 + q4 * 4 + r) * 72 + nt * 16 + l16] = f2bf(c[r] + bias);
        }
    }
    {   // hv[m=wave][d=lane]
        int m = wave, d = lane;
        float acc = wssum[m] * P.bv_emb[m * ND + d];
        const float* We = P.Wv_emb + (size_t)m * NF * ND;
        for (int f = 0; f < NF; f++) acc += xw[m][f] * We[f * ND + d];
        hv[m][d] = acc;
    }
    __syncthreads();

    // ======== E4: pvc[m] ========
    {
        int m = wave, d = lane;
        float acc = wssum[m] * P.bv_val[m * ND + d];
        const float* Wv = P.Wv_val + (size_t)m * ND * ND;
        for (int k = 0; k < ND; k++) acc += hv[m][k] * Wv[k * ND + d];
        pvc[m][d] = acc;
    }
    __syncthreads();

    // ======== E5: r_in partials ========
    {
        int d = lane, w = wave;
        float acc = 0.0f;
        if (w < 2) {
            const float* ga = P.g_anc + (size_t)b * NOBS;
            for (int f = w * 32; f < w * 32 + 32; f++)
                acc += ga[f] * P.r_Win[f * NHID + d];
        } else {
            for (int f = (w - 2) * 32; f < (w - 2) * 32 + 32; f++) {
                float cv = 0.25f * (pvc[0][f] + pvc[1][f] + pvc[2][f] + pvc[3][f]);
                acc += cv * P.r_Win[(NOBS + f) * NHID + d];
            }
        }
        part[w][d] = acc;
    }
    __syncthreads();

    // ======== E6: LN + gelu ========
    if (t < ND) {
        float acc = P.r_bin[t] + part[0][t] + part[1][t] + part[2][t] + part[3][t];
        float mean = wsum64(acc) * (1.0f / 64.0f);
        float dv = acc - mean;
        float var = wsum64(dv * dv) * (1.0f / 64.0f);
        sB[t] = gelu_f(dv * rsqrtf(var + 1e-5f) * P.r_lng[t] + P.r_lnb[t]);
    }
    __syncthreads();

    // ======== E7/E8: r_W1 ========
    {
        int d = lane, w = wave;
        float acc = 0.0f;
        for (int k = w * 16; k < w * 16 + 16; k++) acc += sB[k] * P.r_W1[k * NHID + d];
        part[w][d] = acc;
    }
    __syncthreads();
    if (t < ND) sA[t] = gelu_f(P.r_b1[t] + part[0][t] + part[1][t] + part[2][t] + part[3][t]);
    __syncthreads();

    // ======== E9/E10: r_W2 ========
    {
        int d = lane, w = wave;
        float acc = 0.0f;
        for (int k = w * 16; k < w * 16 + 16; k++) acc += sA[k] * P.r_W2[k * NHID + d];
        part[w][d] = acc;
    }
    __syncthreads();
    if (t < ND) hfin[t] = gelu_f(P.r_b2[t] + part[0][t] + part[1][t] + part[2][t] + part[3][t]);
    __syncthreads();

    // ======== E11: pi_raw + beta ========
    if (t < 16) {
        int h = t >> 2, mm = t & 3;
        float acc = P.r_bview[t];
        for (int k = 0; k < NHID; k++) acc += hfin[k] * P.r_Wview[(h * NHID + k) * 4 + mm];
        pi_raw[t] = acc;
    } else if (t >= 64 && t < 64 + NH) {
        int h = t - 64;
        float acc = P.r_bmode[h];
        for (int k = 0; k < NHID; k++) acc += hfin[k] * P.r_Wmode[h * NHID + k];
        beta_s[h] = 1.0f / (1.0f + expf(-acc));
    }
    __syncthreads();

    // ======== E12: softmax(pi) + gate ========
    {
        int h = wave;
        float p0 = pi_raw[h * 4 + 0], p1 = pi_raw[h * 4 + 1];
        float p2 = pi_raw[h * 4 + 2], p3 = pi_raw[h * 4 + 3];
        float mx = fmaxf(fmaxf(p0, p1), fmaxf(p2, p3));
        float e0 = expf(p0 - mx), e1 = expf(p1 - mx), e2 = expf(p2 - mx), e3 = expf(p3 - mx);
        float inv = 1.0f / (e0 + e1 + e2 + e3);
        e0 *= inv; e1 *= inv; e2 *= inv; e3 *= inv;
        if (lane == 0) {
            pi_s[h * 4 + 0] = e0; pi_s[h * 4 + 1] = e1;
            pi_s[h * 4 + 2] = e2; pi_s[h * 4 + 3] = e3;
        }
        int n = lane;
        float wv = e0 * ew_s[n * 4 + 0] + e1 * ew_s[n * 4 + 1]
                 + e2 * ew_s[n * 4 + 2] + e3 * ew_s[n * 4 + 3];
        gate_s[h * 64 + n] = logf(wv + EPSC);
    }
    __syncthreads();

    // ======== attention + FF layers ========
    const float inv_tau = 0.25f * expf(-P.log_tau[wave]);
    for (int l = 0; l < NLAYER; l++) {
        const float* Wq  = P.L_Wq  + l * ND * ND;
        const float* Wo  = P.L_Wo  + l * ND * ND;
        const float* ln1g = P.L_ln1g + l * ND;
        const float* ln1b = P.L_ln1b + l * ND;
        const float* ln2g = P.L_ln2g + l * ND;
        const float* ln2b = P.L_ln2b + l * ND;
        const float* Wf1 = P.L_Wf1 + l * ND * NFF;
        const float* bf1 = P.L_bf1 + l * NFF;
        const float* Wf2 = P.L_Wf2 + l * NFF * ND;
        const float* bf2 = P.L_bf2 + l * ND;
        const unsigned short* wK = P.wpack + WS_WK + l * 4096;
        const unsigned short* wV = P.wpack + WS_WV + l * 4096;

        // --- L-E1: K then V via MFMA (one accumulator live at a time) ---
        {
            const int m0 = wave * 16;
            const int arow = (m0 + l16) * 72 + q4 * 8;
#pragma unroll
            for (int nt = 0; nt < 4; nt++) {
                short8 a0 = *(const short8*)&hb[arow];
                short8 a1 = *(const short8*)&hb[arow + 32];
                short8 b0 = *(const short8*)&wK[(nt * 16 + l16) * 64 + q4 * 8];
                short8 b1 = *(const short8*)&wK[(nt * 16 + l16) * 64 + 32 + q4 * 8];
                floatx4 c = (floatx4){0.f, 0.f, 0.f, 0.f};
                c = __builtin_amdgcn_mfma_f32_16x16x32_bf16(a0, b0, c, 0, 0, 0);
                c = __builtin_amdgcn_mfma_f32_16x16x32_bf16(a1, b1, c, 0, 0, 0);
#pragma unroll
                for (int r = 0; r < 4; r++)
                    R1.kv.kb[(m0 + q4 * 4 + r) * 66 + nt * 16 + l16] = f2bf(c[r]);
            }
#pragma unroll
            for (int nt = 0; nt < 4; nt++) {
                short8 a0 = *(const short8*)&hb[arow];
                short8 a1 = *(const short8*)&hb[arow + 32];
                short8 b0 = *(const short8*)&wV[(nt * 16 + l16) * 64 + q4 * 8];
                short8 b1 = *(const short8*)&wV[(nt * 16 + l16) * 64 + 32 + q4 * 8];
                floatx4 c = (floatx4){0.f, 0.f, 0.f, 0.f};
                c = __builtin_amdgcn_mfma_f32_16x16x32_bf16(a0, b0, c, 0, 0, 0);
                c = __builtin_amdgcn_mfma_f32_16x16x32_bf16(a1, b1, c, 0, 0, 0);
#pragma unroll
                for (int r = 0; r < 4; r++)
                    R1.kv.vb[(m0 + q4 * 4 + r) * 66 + nt * 16 + l16] = f2bf(c[r]);
            }
        }
        if (t < ND) {
            float acc = 0.0f;
            for (int k = 0; k < ND; k++) acc += xcur[k] * Wq[k * ND + t];
            qv[t] = acc;
        }
        __syncthreads();

        // --- L-E2: scores + softmax (wave = head) ---
        {
            int h = wave, n = lane;
            float s = 0.0f;
#pragma unroll
            for (int j = 0; j < 16; j++)
                s += qv[h * 16 + j] * bf2f(R1.kv.kb[n * 66 + h * 16 + j]);
            s = s * inv_tau + gate_s[h * 64 + n];
            float mx = wmax64(s);
            float e = expf(s - mx);
            float se = wsum64(e);
            attn_s[h * 64 + n] = e / se;
        }
        __syncthreads();

        // --- L-E3: ctx ---
        if (t < ND) {
            int h = t >> 4;
            float acc = 0.0f;
            for (int n = 0; n < NN; n++)
                acc += attn_s[h * 64 + n] * bf2f(R1.kv.vb[n * 66 + t]);
            ctx_s[t] = acc;
        }
        __syncthreads();

        // --- L-E4: Wo partials ---
        {
            int d = lane, w = wave;
            float acc = 0.0f;
            for (int c = w * 16; c < w * 16 + 16; c++) acc += ctx_s[c] * Wo[c * ND + d];
            part[w][d] = acc;
        }
        __syncthreads();

        // --- L-E5: residual + LN1 ---
        if (t < ND) {
            float xv = xcur[t] + part[0][t] + part[1][t] + part[2][t] + part[3][t];
            float mean = wsum64(xv) * (1.0f / 64.0f);
            float dv = xv - mean;
            float var = wsum64(dv * dv) * (1.0f / 64.0f);
            xcur[t] = dv * rsqrtf(var + 1e-5f) * ln1g[t] + ln1b[t];
        }
        __syncthreads();

        // --- L-E6: FF1 partials ---
        {
            int j = t & 127, w2 = t >> 7;
            float acc = 0.0f;
            for (int k = w2 * 32; k < w2 * 32 + 32; k++) acc += xcur[k] * Wf1[k * NFF + j];
            part[w2][j] = acc;
        }
        __syncthreads();

        // --- L-E7: gelu -> ffs ---
        if (t < NFF) ffs[t] = gelu_f(bf1[t] + part[0][t] + part[1][t]);
        __syncthreads();

        // --- L-E8: FF2 partials ---
        {
            int d = lane, w = wave;
            float acc = 0.0f;
            for (int k = w * 32; k < w * 32 + 32; k++) acc += ffs[k] * Wf2[k * ND + d];
            part[w][d] = acc;
        }
        __syncthreads();

        // --- L-E9: residual + LN2 ---
        if (t < ND) {
            float xv = xcur[t] + bf2[t] + part[0][t] + part[1][t] + part[2][t] + part[3][t];
            float mean = wsum64(xv) * (1.0f / 64.0f);
            float dv = xv - mean;
            float var = wsum64(dv * dv) * (1.0f / 64.0f);
            xcur[t] = dv * rsqrtf(var + 1e-5f) * ln2g[t] + ln2b[t];
        }
        __syncthreads();
    }

    // ======== blended + final head ========
    if (t < ND) {
        float acc = 0.0f;
#pragma unroll
        for (int h = 0; h < NH; h++) {
            float iso = pi_s[h * 4 + 0] * pvc[0][t] + pi_s[h * 4 + 1] * pvc[1][t]
                      + pi_s[h * 4 + 2] * pvc[2][t] + pi_s[h * 4 + 3] * pvc[3][t];
            acc += (1.0f - beta_s[h]) * iso + beta_s[h] * xcur[t];
        }
        float bl = acc * 0.25f;
        float mean = wsum64(bl) * (1.0f / 64.0f);
        float dv = bl - mean;
        float var = wsum64(dv * dv) * (1.0f / 64.0f);
        sA[t] = dv * rsqrtf(var + 1e-5f) * P.p_lng[t] + P.p_lnb[t];
    }
    __syncthreads();
    if (t < 32) {
        float acc = P.p_b1[t];
        for (int d = 0; d < ND; d++) acc += sA[d] * P.p_W1[d * 32 + t];
        sB[t] = gelu_f(acc);
    }
    __syncthreads();
    if (t < NOUT) {
        float acc = P.p_b2[t];
        for (int j = 0; j < 32; j++) acc += sB[j] * P.p_W2[j * NOUT + t];
        P.out[(size_t)b * NOUT + t] = acc;
    }
}

extern "C" void kernel_launch(void* const* d_in, const int* in_sizes, int n_in,
                              void* d_out, int out_size, void* d_ws, size_t ws_size,
                              hipStream_t stream)
{
    (void)in_sizes; (void)n_in; (void)ws_size; (void)out_size;
    unsigned short* wsb = (unsigned short*)d_ws;
    // FIXED: L_Wk is d_in[24], L_Wv is d_in[25]  (d_in[23] is L_Wq!)
    hipLaunchKernelGGL(prepack_w, dim3(96), dim3(256), 0, stream,
                       (const float*)d_in[6], (const float*)d_in[24],
                       (const float*)d_in[25], wsb);
    GParams P;
    P.x_anc   = (const float*)d_in[0];
    P.g_anc   = (const float*)d_in[1];
    P.x_nei   = (const float*)d_in[2];
    P.ew_anc  = (const float*)d_in[3];
    P.W_anc   = (const float*)d_in[4];
    P.b_anc   = (const float*)d_in[5];
    P.Wv_emb  = (const float*)d_in[6];
    P.bv_emb  = (const float*)d_in[7];
    P.Wv_val  = (const float*)d_in[8];
    P.bv_val  = (const float*)d_in[9];
    P.r_Win   = (const float*)d_in[10];
    P.r_bin   = (const float*)d_in[11];
    P.r_lng   = (const float*)d_in[12];
    P.r_lnb   = (const float*)d_in[13];
    P.r_W1    = (const float*)d_in[14];
    P.r_b1    = (const float*)d_in[15];
    P.r_W2    = (const float*)d_in[16];
    P.r_b2    = (const float*)d_in[17];
    P.r_Wview = (const float*)d_in[18];
    P.r_bview = (const float*)d_in[19];
    P.r_Wmode = (const float*)d_in[20];
    P.r_bmode = (const float*)d_in[21];
    P.log_tau = (const float*)d_in[22];
    P.L_Wq    = (const float*)d_in[23];
    P.L_Wk    = (const float*)d_in[24];
    P.L_Wv    = (const float*)d_in[25];
    P.L_Wo    = (const float*)d_in[26];
    P.L_ln1g  = (const float*)d_in[27];
    P.L_ln1b  = (const float*)d_in[28];
    P.L_ln2g  = (const float*)d_in[29];
    P.L_ln2b  = (const float*)d_in[30];
    P.L_Wf1   = (const float*)d_in[31];
    P.L_bf1   = (const float*)d_in[32];
    P.L_Wf2   = (const float*)d_in[33];
    P.L_bf2   = (const float*)d_in[34];
    P.p_lng   = (const float*)d_in[35];
    P.p_lnb   = (const float*)d_in[36];
    P.p_W1    = (const float*)d_in[37];
    P.p_b1    = (const float*)d_in[38];
    P.p_W2    = (const float*)d_in[39];
    P.p_b2    = (const float*)d_in[40];
    P.wpack   = wsb;
    P.out     = (float*)d_out;
    hipLaunchKernelGGL(gora_fused, dim3(NB), dim3(256), 0, stream, P);
}

// Round 5
// 712.300 us; speedup vs baseline: 1.4258x; 1.0939x over previous
//
#include <hip/hip_runtime.h>
#include <hip/hip_bf16.h>
#include <math.h>

#define NB 4096
#define NN 64
#define NM 4
#define NF 128
#define NOBS 64
#define ND 64
#define NH 4
#define NLAYER 2
#define NFF 128
#define NHID 64
#define NOUT 8
#define EPSC 1e-6f

// packed-weight layout in d_ws (unsigned short = bf16):
//   [0      , 8192 )  wE : Wv_emb view0, [col n=0..63][k=0..127]
//   [8192   , 16384)  wK : L_Wk, [l][col n][k]  (k=0..63)
//   [16384  , 24576)  wV : L_Wv, [l][col n][k]
#define WS_WE 0
#define WS_WK 8192
#define WS_WV 16384

typedef __attribute__((ext_vector_type(8))) short short8;
typedef __attribute__((ext_vector_type(4))) float floatx4;

struct GParams {
    const float* x_anc; const float* g_anc; const float* x_nei; const float* ew_anc;
    const float* W_anc; const float* b_anc;
    const float* Wv_emb; const float* bv_emb; const float* Wv_val; const float* bv_val;
    const float* r_Win; const float* r_bin; const float* r_lng; const float* r_lnb;
    const float* r_W1; const float* r_b1; const float* r_W2; const float* r_b2;
    const float* r_Wview; const float* r_bview; const float* r_Wmode; const float* r_bmode;
    const float* log_tau;
    const float* L_Wq; const float* L_Wk; const float* L_Wv; const float* L_Wo;
    const float* L_ln1g; const float* L_ln1b; const float* L_ln2g; const float* L_ln2b;
    const float* L_Wf1; const float* L_bf1; const float* L_Wf2; const float* L_bf2;
    const float* p_lng; const float* p_lnb; const float* p_W1; const float* p_b1;
    const float* p_W2; const float* p_b2;
    const unsigned short* wpack;
    float* out;
};

__device__ __forceinline__ float gelu_f(float x) {
    return 0.5f * x * (1.0f + erff(x * 0.7071067811865476f));
}
__device__ __forceinline__ float wsum64(float v) {
#pragma unroll
    for (int off = 32; off > 0; off >>= 1) v += __shfl_xor(v, off, 64);
    return v;
}
__device__ __forceinline__ float wmax64(float v) {
#pragma unroll
    for (int off = 32; off > 0; off >>= 1) v = fmaxf(v, __shfl_xor(v, off, 64));
    return v;
}
// bf16 round-nearest-even, bit-level (finite inputs only)
__device__ __forceinline__ unsigned short f2bf(float f) {
    unsigned int u = __float_as_uint(f);
    unsigned int r = (u + 0x7fffu + ((u >> 16) & 1u)) >> 16;
    return (unsigned short)r;
}
__device__ __forceinline__ float bf2f(unsigned short s) {
    return __uint_as_float(((unsigned int)s) << 16);
}
__device__ __forceinline__ unsigned int pack2(float lo, float hi) {
    return (unsigned int)f2bf(lo) | ((unsigned int)f2bf(hi) << 16);
}

// ---- prepack: fp32 weights -> bf16, B-fragment-friendly [col][k] layout ----
__global__ __launch_bounds__(256)
void prepack_w(const float* Wv_emb, const float* L_Wk, const float* L_Wv,
               unsigned short* ws)
{
    int i = blockIdx.x * 256 + threadIdx.x;          // 24576 total
    if (i < 8192) {
        int n = i >> 7, k = i & 127;                 // wE[n*128+k] = Wv_emb[0][k][n]
        ws[WS_WE + i] = f2bf(Wv_emb[k * ND + n]);
    } else if (i < 16384) {
        int j = i - 8192;
        int l = j >> 12, r = j & 4095, n = r >> 6, k = r & 63;
        ws[i] = f2bf(L_Wk[l * 4096 + k * ND + n]);
    } else if (i < 24576) {
        int j = i - 16384;
        int l = j >> 12, r = j & 4095, n = r >> 6, k = r & 63;
        ws[i] = f2bf(L_Wv[l * 4096 + k * ND + n]);
    }
}

// (256,2): VGPR budget 256/wave -> no scratch spills, deep load pipelining.
// (256,4) capped at 128 VGPR -> 64 VGPR + 25KB/block scratch, serialized loads (R4).
__global__ __launch_bounds__(256, 2)
void gora_fused(GParams P)
{
    const int b = blockIdx.x;
    const int t = threadIdx.x;
    const int lane = t & 63;
    const int wave = t >> 6;
    const int l16 = lane & 15;   // col within 16x16 tile
    const int q4  = lane >> 4;   // quad

    // ---- LDS: region1 (x_nei staging) aliased with K/V buffers ----
    __shared__ __align__(16) union Reg1 {
        unsigned short xsf[NN * 136];                       // 17408 B
        struct { unsigned short kb[NN * 66]; unsigned short vb[NN * 66]; } kv;
    } R1;
    __shared__ __align__(16) unsigned short hb[NN * 72];    // h_nei_shared bf16
    __shared__ float ew_s[NN * NM];
    __shared__ float winv[NM], wssum[NM];
    __shared__ float xw[NM][NF];
    __shared__ float hv[NM][ND];
    __shared__ float pvc[NM][ND];
    __shared__ float part[4][NF];
    __shared__ float hfin[NHID];
    __shared__ float pi_raw[16];
    __shared__ float pi_s[16];
    __shared__ float beta_s[NH];
    __shared__ float gate_s[NH * NN];
    __shared__ float xcur[ND];
    __shared__ float qv[ND];
    __shared__ float attn_s[NH * NN];
    __shared__ float ctx_s[ND];
    __shared__ float ffs[NFF];
    __shared__ float sA[ND];
    __shared__ float sB[ND];

    // ================= E0: loads =================
    {
        float e = P.ew_anc[(size_t)b * 256 + t];
        ew_s[t] = (e > 0.0f) ? e : 0.0f;
    }
    {
        const float4* xn4 = (const float4*)(P.x_nei + (size_t)b * NN * NF);
#pragma unroll
        for (int i = 0; i < 4; i++) {
            int p = t + i * 256;                 // float8 index, 1024 total
            float4 a0 = xn4[2 * p];
            float4 a1 = xn4[2 * p + 1];
            int e8 = p * 8, n = e8 >> 7, f = e8 & 127;
            int4 pk;
            pk.x = (int)pack2(a0.x, a0.y);
            pk.y = (int)pack2(a0.z, a0.w);
            pk.z = (int)pack2(a1.x, a1.y);
            pk.w = (int)pack2(a1.z, a1.w);
            *(int4*)&R1.xsf[n * 136 + f] = pk;
        }
    }
    __syncthreads();

    // ======== E1: view-weight norms + h_anc partials ========
    if (t < NM) {
        float ssum = 0.0f;
        for (int n = 0; n < NN; n++) ssum += ew_s[n * 4 + t];
        float c = fmaxf(ssum, EPSC);
        winv[t] = 1.0f / c;
        wssum[t] = ssum / c;
    }
    {
        const float* xa = P.x_anc + (size_t)b * NF;
        float acc = 0.0f;
        for (int f = wave * 32; f < wave * 32 + 32; f++)
            acc += xa[f] * P.W_anc[f * ND + lane];
        part[wave][lane] = acc;
    }
    __syncthreads();

    // ======== E2: xcur = h_anc ; xw[m][f] ========
    if (t < ND)
        xcur[t] = P.b_anc[t] + part[0][t] + part[1][t] + part[2][t] + part[3][t];
    {
        int f = t & 127, m0 = t >> 7;
        float a0 = 0.f, a1 = 0.f;
        for (int n = 0; n < NN; n++) {
            float xv = bf2f(R1.xsf[n * 136 + f]);
            a0 += ew_s[n * 4 + m0] * xv;
            a1 += ew_s[n * 4 + m0 + 2] * xv;
        }
        xw[m0][f]     = a0 * winv[m0];
        xw[m0 + 2][f] = a1 * winv[m0 + 2];
    }
    __syncthreads();

    // ======== E3: h_nei_shared via MFMA (prepacked B) + hv ========
    {
        const int m0 = wave * 16;
        const unsigned short* wE = P.wpack + WS_WE;
#pragma unroll
        for (int nt = 0; nt < 4; nt++) {
            floatx4 c = (floatx4){0.f, 0.f, 0.f, 0.f};
#pragma unroll
            for (int k0 = 0; k0 < NF; k0 += 32) {
                short8 a  = *(const short8*)&R1.xsf[(m0 + l16) * 136 + k0 + q4 * 8];
                short8 bb = *(const short8*)&wE[(nt * 16 + l16) * 128 + k0 + q4 * 8];
                c = __builtin_amdgcn_mfma_f32_16x16x32_bf16(a, bb, c, 0, 0, 0);
            }
            float bias = P.bv_emb[nt * 16 + l16];
#pragma unroll
            for (int r = 0; r < 4; r++)
                hb[(m0 + q4 * 4 + r) * 72 + nt * 16 + l16] = f2bf(c[r] + bias);
        }
    }
    {   // hv[m=wave][d=lane]
        int m = wave, d = lane;
        float acc = wssum[m] * P.bv_emb[m * ND + d];
        const float* We = P.Wv_emb + (size_t)m * NF * ND;
        for (int f = 0; f < NF; f++) acc += xw[m][f] * We[f * ND + d];
        hv[m][d] = acc;
    }
    __syncthreads();

    // ======== E4: pvc[m] ========
    {
        int m = wave, d = lane;
        float acc = wssum[m] * P.bv_val[m * ND + d];
        const float* Wv = P.Wv_val + (size_t)m * ND * ND;
        for (int k = 0; k < ND; k++) acc += hv[m][k] * Wv[k * ND + d];
        pvc[m][d] = acc;
    }
    __syncthreads();

    // ======== E5: r_in partials ========
    {
        int d = lane, w = wave;
        float acc = 0.0f;
        if (w < 2) {
            const float* ga = P.g_anc + (size_t)b * NOBS;
            for (int f = w * 32; f < w * 32 + 32; f++)
                acc += ga[f] * P.r_Win[f * NHID + d];
        } else {
            for (int f = (w - 2) * 32; f < (w - 2) * 32 + 32; f++) {
                float cv = 0.25f * (pvc[0][f] + pvc[1][f] + pvc[2][f] + pvc[3][f]);
                acc += cv * P.r_Win[(NOBS + f) * NHID + d];
            }
        }
        part[w][d] = acc;
    }
    __syncthreads();

    // ======== E6: LN + gelu ========
    if (t < ND) {
        float acc = P.r_bin[t] + part[0][t] + part[1][t] + part[2][t] + part[3][t];
        float mean = wsum64(acc) * (1.0f / 64.0f);
        float dv = acc - mean;
        float var = wsum64(dv * dv) * (1.0f / 64.0f);
        sB[t] = gelu_f(dv * rsqrtf(var + 1e-5f) * P.r_lng[t] + P.r_lnb[t]);
    }
    __syncthreads();

    // ======== E7/E8: r_W1 ========
    {
        int d = lane, w = wave;
        float acc = 0.0f;
        for (int k = w * 16; k < w * 16 + 16; k++) acc += sB[k] * P.r_W1[k * NHID + d];
        part[w][d] = acc;
    }
    __syncthreads();
    if (t < ND) sA[t] = gelu_f(P.r_b1[t] + part[0][t] + part[1][t] + part[2][t] + part[3][t]);
    __syncthreads();

    // ======== E9/E10: r_W2 ========
    {
        int d = lane, w = wave;
        float acc = 0.0f;
        for (int k = w * 16; k < w * 16 + 16; k++) acc += sA[k] * P.r_W2[k * NHID + d];
        part[w][d] = acc;
    }
    __syncthreads();
    if (t < ND) hfin[t] = gelu_f(P.r_b2[t] + part[0][t] + part[1][t] + part[2][t] + part[3][t]);
    __syncthreads();

    // ======== E11: pi_raw + beta ========
    if (t < 16) {
        int h = t >> 2, mm = t & 3;
        float acc = P.r_bview[t];
        for (int k = 0; k < NHID; k++) acc += hfin[k] * P.r_Wview[(h * NHID + k) * 4 + mm];
        pi_raw[t] = acc;
    } else if (t >= 64 && t < 64 + NH) {
        int h = t - 64;
        float acc = P.r_bmode[h];
        for (int k = 0; k < NHID; k++) acc += hfin[k] * P.r_Wmode[h * NHID + k];
        beta_s[h] = 1.0f / (1.0f + expf(-acc));
    }
    __syncthreads();

    // ======== E12: softmax(pi) + gate ========
    {
        int h = wave;
        float p0 = pi_raw[h * 4 + 0], p1 = pi_raw[h * 4 + 1];
        float p2 = pi_raw[h * 4 + 2], p3 = pi_raw[h * 4 + 3];
        float mx = fmaxf(fmaxf(p0, p1), fmaxf(p2, p3));
        float e0 = expf(p0 - mx), e1 = expf(p1 - mx), e2 = expf(p2 - mx), e3 = expf(p3 - mx);
        float inv = 1.0f / (e0 + e1 + e2 + e3);
        e0 *= inv; e1 *= inv; e2 *= inv; e3 *= inv;
        if (lane == 0) {
            pi_s[h * 4 + 0] = e0; pi_s[h * 4 + 1] = e1;
            pi_s[h * 4 + 2] = e2; pi_s[h * 4 + 3] = e3;
        }
        int n = lane;
        float wv = e0 * ew_s[n * 4 + 0] + e1 * ew_s[n * 4 + 1]
                 + e2 * ew_s[n * 4 + 2] + e3 * ew_s[n * 4 + 3];
        gate_s[h * 64 + n] = logf(wv + EPSC);
    }
    __syncthreads();

    // ======== attention + FF layers ========
    const float inv_tau = 0.25f * expf(-P.log_tau[wave]);
    for (int l = 0; l < NLAYER; l++) {
        const float* Wq  = P.L_Wq  + l * ND * ND;
        const float* Wo  = P.L_Wo  + l * ND * ND;
        const float* ln1g = P.L_ln1g + l * ND;
        const float* ln1b = P.L_ln1b + l * ND;
        const float* ln2g = P.L_ln2g + l * ND;
        const float* ln2b = P.L_ln2b + l * ND;
        const float* Wf1 = P.L_Wf1 + l * ND * NFF;
        const float* bf1 = P.L_bf1 + l * NFF;
        const float* Wf2 = P.L_Wf2 + l * NFF * ND;
        const float* bf2 = P.L_bf2 + l * ND;
        const unsigned short* wK = P.wpack + WS_WK + l * 4096;
        const unsigned short* wV = P.wpack + WS_WV + l * 4096;

        // --- L-E1: K then V via MFMA (one accumulator live at a time) ---
        {
            const int m0 = wave * 16;
            const int arow = (m0 + l16) * 72 + q4 * 8;
#pragma unroll
            for (int nt = 0; nt < 4; nt++) {
                short8 a0 = *(const short8*)&hb[arow];
                short8 a1 = *(const short8*)&hb[arow + 32];
                short8 b0 = *(const short8*)&wK[(nt * 16 + l16) * 64 + q4 * 8];
                short8 b1 = *(const short8*)&wK[(nt * 16 + l16) * 64 + 32 + q4 * 8];
                floatx4 c = (floatx4){0.f, 0.f, 0.f, 0.f};
                c = __builtin_amdgcn_mfma_f32_16x16x32_bf16(a0, b0, c, 0, 0, 0);
                c = __builtin_amdgcn_mfma_f32_16x16x32_bf16(a1, b1, c, 0, 0, 0);
#pragma unroll
                for (int r = 0; r < 4; r++)
                    R1.kv.kb[(m0 + q4 * 4 + r) * 66 + nt * 16 + l16] = f2bf(c[r]);
            }
#pragma unroll
            for (int nt = 0; nt < 4; nt++) {
                short8 a0 = *(const short8*)&hb[arow];
                short8 a1 = *(const short8*)&hb[arow + 32];
                short8 b0 = *(const short8*)&wV[(nt * 16 + l16) * 64 + q4 * 8];
                short8 b1 = *(const short8*)&wV[(nt * 16 + l16) * 64 + 32 + q4 * 8];
                floatx4 c = (floatx4){0.f, 0.f, 0.f, 0.f};
                c = __builtin_amdgcn_mfma_f32_16x16x32_bf16(a0, b0, c, 0, 0, 0);
                c = __builtin_amdgcn_mfma_f32_16x16x32_bf16(a1, b1, c, 0, 0, 0);
#pragma unroll
                for (int r = 0; r < 4; r++)
                    R1.kv.vb[(m0 + q4 * 4 + r) * 66 + nt * 16 + l16] = f2bf(c[r]);
            }
        }
        if (t < ND) {
            float acc = 0.0f;
            for (int k = 0; k < ND; k++) acc += xcur[k] * Wq[k * ND + t];
            qv[t] = acc;
        }
        __syncthreads();

        // --- L-E2: scores + softmax (wave = head) ---
        {
            int h = wave, n = lane;
            float s = 0.0f;
#pragma unroll
            for (int j = 0; j < 16; j++)
                s += qv[h * 16 + j] * bf2f(R1.kv.kb[n * 66 + h * 16 + j]);
            s = s * inv_tau + gate_s[h * 64 + n];
            float mx = wmax64(s);
            float e = expf(s - mx);
            float se = wsum64(e);
            attn_s[h * 64 + n] = e / se;
        }
        __syncthreads();

        // --- L-E3: ctx ---
        if (t < ND) {
            int h = t >> 4;
            float acc = 0.0f;
            for (int n = 0; n < NN; n++)
                acc += attn_s[h * 64 + n] * bf2f(R1.kv.vb[n * 66 + t]);
            ctx_s[t] = acc;
        }
        __syncthreads();

        // --- L-E4: Wo partials ---
        {
            int d = lane, w = wave;
            float acc = 0.0f;
            for (int c = w * 16; c < w * 16 + 16; c++) acc += ctx_s[c] * Wo[c * ND + d];
            part[w][d] = acc;
        }
        __syncthreads();

        // --- L-E5: residual + LN1 ---
        if (t < ND) {
            float xv = xcur[t] + part[0][t] + part[1][t] + part[2][t] + part[3][t];
            float mean = wsum64(xv) * (1.0f / 64.0f);
            float dv = xv - mean;
            float var = wsum64(dv * dv) * (1.0f / 64.0f);
            xcur[t] = dv * rsqrtf(var + 1e-5f) * ln1g[t] + ln1b[t];
        }
        __syncthreads();

        // --- L-E6: FF1 partials ---
        {
            int j = t & 127, w2 = t >> 7;
            float acc = 0.0f;
            for (int k = w2 * 32; k < w2 * 32 + 32; k++) acc += xcur[k] * Wf1[k * NFF + j];
            part[w2][j] = acc;
        }
        __syncthreads();

        // --- L-E7: gelu -> ffs ---
        if (t < NFF) ffs[t] = gelu_f(bf1[t] + part[0][t] + part[1][t]);
        __syncthreads();

        // --- L-E8: FF2 partials ---
        {
            int d = lane, w = wave;
            float acc = 0.0f;
            for (int k = w * 32; k < w * 32 + 32; k++) acc += ffs[k] * Wf2[k * ND + d];
            part[w][d] = acc;
        }
        __syncthreads();

        // --- L-E9: residual + LN2 ---
        if (t < ND) {
            float xv = xcur[t] + bf2[t] + part[0][t] + part[1][t] + part[2][t] + part[3][t];
            float mean = wsum64(xv) * (1.0f / 64.0f);
            float dv = xv - mean;
            float var = wsum64(dv * dv) * (1.0f / 64.0f);
            xcur[t] = dv * rsqrtf(var + 1e-5f) * ln2g[t] + ln2b[t];
        }
        __syncthreads();
    }

    // ======== blended + final head ========
    if (t < ND) {
        float acc = 0.0f;
#pragma unroll
        for (int h = 0; h < NH; h++) {
            float iso = pi_s[h * 4 + 0] * pvc[0][t] + pi_s[h * 4 + 1] * pvc[1][t]
                      + pi_s[h * 4 + 2] * pvc[2][t] + pi_s[h * 4 + 3] * pvc[3][t];
            acc += (1.0f - beta_s[h]) * iso + beta_s[h] * xcur[t];
        }
        float bl = acc * 0.25f;
        float mean = wsum64(bl) * (1.0f / 64.0f);
        float dv = bl - mean;
        float var = wsum64(dv * dv) * (1.0f / 64.0f);
        sA[t] = dv * rsqrtf(var + 1e-5f) * P.p_lng[t] + P.p_lnb[t];
    }
    __syncthreads();
    if (t < 32) {
        float acc = P.p_b1[t];
        for (int d = 0; d < ND; d++) acc += sA[d] * P.p_W1[d * 32 + t];
        sB[t] = gelu_f(acc);
    }
    __syncthreads();
    if (t < NOUT) {
        float acc = P.p_b2[t];
        for (int j = 0; j < 32; j++) acc += sB[j] * P.p_W2[j * NOUT + t];
        P.out[(size_t)b * NOUT + t] = acc;
    }
}

extern "C" void kernel_launch(void* const* d_in, const int* in_sizes, int n_in,
                              void* d_out, int out_size, void* d_ws, size_t ws_size,
                              hipStream_t stream)
{
    (void)in_sizes; (void)n_in; (void)ws_size; (void)out_size;
    unsigned short* wsb = (unsigned short*)d_ws;
    hipLaunchKernelGGL(prepack_w, dim3(96), dim3(256), 0, stream,
                       (const float*)d_in[6], (const float*)d_in[24],
                       (const float*)d_in[25], wsb);
    GParams P;
    P.x_anc   = (const float*)d_in[0];
    P.g_anc   = (const float*)d_in[1];
    P.x_nei   = (const float*)d_in[2];
    P.ew_anc  = (const float*)d_in[3];
    P.W_anc   = (const float*)d_in[4];
    P.b_anc   = (const float*)d_in[5];
    P.Wv_emb  = (const float*)d_in[6];
    P.bv_emb  = (const float*)d_in[7];
    P.Wv_val  = (const float*)d_in[8];
    P.bv_val  = (const float*)d_in[9];
    P.r_Win   = (const float*)d_in[10];
    P.r_bin   = (const float*)d_in[11];
    P.r_lng   = (const float*)d_in[12];
    P.r_lnb   = (const float*)d_in[13];
    P.r_W1    = (const float*)d_in[14];
    P.r_b1    = (const float*)d_in[15];
    P.r_W2    = (const float*)d_in[16];
    P.r_b2    = (const float*)d_in[17];
    P.r_Wview = (const float*)d_in[18];
    P.r_bview = (const float*)d_in[19];
    P.r_Wmode = (const float*)d_in[20];
    P.r_bmode = (const float*)d_in[21];
    P.log_tau = (const float*)d_in[22];
    P.L_Wq    = (const float*)d_in[23];
    P.L_Wk    = (const float*)d_in[24];
    P.L_Wv    = (const float*)d_in[25];
    P.L_Wo    = (const float*)d_in[26];
    P.L_ln1g  = (const float*)d_in[27];
    P.L_ln1b  = (const float*)d_in[28];
    P.L_ln2g  = (const float*)d_in[29];
    P.L_ln2b  = (const float*)d_in[30];
    P.L_Wf1   = (const float*)d_in[31];
    P.L_bf1   = (const float*)d_in[32];
    P.L_Wf2   = (const float*)d_in[33];
    P.L_bf2   = (const float*)d_in[34];
    P.p_lng   = (const float*)d_in[35];
    P.p_lnb   = (const float*)d_in[36];
    P.p_W1    = (const float*)d_in[37];
    P.p_b1    = (const float*)d_in[38];
    P.p_W2    = (const float*)d_in[39];
    P.p_b2    = (const float*)d_in[40];
    P.wpack   = wsb;
    P.out     = (float*)d_out;
    hipLaunchKernelGGL(gora_fused, dim3(NB), dim3(256), 0, stream, P);
}